// Round 10
// baseline (216.000 us; speedup 1.0000x reference)
//
#include <hip/hip_runtime.h>
#include <hip/hip_bf16.h>
#include <math.h>

typedef __hip_bfloat16 bf16;
typedef __attribute__((ext_vector_type(8))) short s16x8;   // 8 bf16 (4 VGPRs)
typedef __attribute__((ext_vector_type(4))) float f32x4;

__device__ __forceinline__ float fsig(float x) {
  return __builtin_amdgcn_rcpf(1.0f + __expf(-x));
}
__device__ __forceinline__ float ftanh(float x) { return 2.0f * fsig(2.0f * x) - 1.0f; }
__device__ __forceinline__ float dot4(float4 a, float4 b) {
  return a.x * b.x + a.y * b.y + a.z * b.z + a.w * b.w;
}
__device__ __forceinline__ float wred(float s) {
#pragma unroll
  for (int off = 32; off > 0; off >>= 1) s += __shfl_down(s, off, 64);
  return s;
}
__device__ __forceinline__ float b2f(unsigned short u) {
  return __uint_as_float((unsigned)u << 16);
}
__device__ __forceinline__ float4 b2f4(ushort4 u) {
  return make_float4(b2f(u.x), b2f(u.y), b2f(u.z), b2f(u.w));
}
__device__ __forceinline__ float dot8(s16x8 v, float4 a, float4 b) {
  return b2f((unsigned short)v[0]) * a.x + b2f((unsigned short)v[1]) * a.y +
         b2f((unsigned short)v[2]) * a.z + b2f((unsigned short)v[3]) * a.w +
         b2f((unsigned short)v[4]) * b.x + b2f((unsigned short)v[5]) * b.y +
         b2f((unsigned short)v[6]) * b.z + b2f((unsigned short)v[7]) * b.w;
}
__device__ __forceinline__ ushort4 f4tob4(float4 v) {
  ushort4 u;
  u.x = __bfloat16_as_ushort(__float2bfloat16(v.x));
  u.y = __bfloat16_as_ushort(__float2bfloat16(v.y));
  u.z = __bfloat16_as_ushort(__float2bfloat16(v.z));
  u.w = __bfloat16_as_ushort(__float2bfloat16(v.w));
  return u;
}

// Wg7 row layout (bf16, 5120 per row): [Wri 0 | Wmig 512 | Wrig 1536 | Wmrg 2048 |
//                                       Wrrg 3072 | Wmwg 3584 | Wrwg 4608]
#define WG7_STRIDE 5120

// ================= setup (bulk Xb/Wcat staging moved to gates_pe riders) =================
// [0,1536):     vectorized casts: Wcat2 left = bf16(W_ho); EW2 left = bf16(W_enc)
// [1536,2560):  Wdt[k][j] = bf16(W_dec[j][k])
// [2560,4096):  merged GEMV: Who rows o<512 -> vout[o]=Who.b_dec, out_s[o]=Who.hidv
//               Wenc rows e=o-512 -> Web[e]=Wenc.b_dec, mem_s[e]=wg*tanh(b_enc+Wenc.hidv)
//               (hidv = step-0 closed form from biases; mem0=0 so no mem read)
// [4096,9216):  cast 7 gate-weight matrices into row-packed bf16 Wg7[1024][5120]
__global__ void setup(const float* __restrict__ W_ho, const float* __restrict__ W_dec,
                      const float* __restrict__ W_enc,
                      const float* __restrict__ Wri, const float* __restrict__ Wmig,
                      const float* __restrict__ Wrig, const float* __restrict__ Wmrg,
                      const float* __restrict__ Wrrg, const float* __restrict__ Wmwg,
                      const float* __restrict__ Wrwg,
                      const float* __restrict__ b_inp, const float* __restrict__ b_rinp,
                      const float* __restrict__ b_ig, const float* __restrict__ b_mig,
                      const float* __restrict__ b_rig, const float* __restrict__ b_wg,
                      const float* __restrict__ b_mwg, const float* __restrict__ b_rwg,
                      const float* __restrict__ b_dec, const float* __restrict__ b_enc,
                      bf16* __restrict__ Wcat2, bf16* __restrict__ Wdt,
                      bf16* __restrict__ EW2,
                      float* __restrict__ out_s, float* __restrict__ mem_s,
                      float* __restrict__ vout, float* __restrict__ Web,
                      bf16* __restrict__ Wg7) {
  __shared__ float t[32][33];
  const int id = blockIdx.x, tid = threadIdx.x;
  if (id < 1536) {
    const int elem = (id * 256 + tid) * 4;  // < 1572864
    if (elem < 524288) {
      const float4 v = *(const float4*)(W_ho + elem);
      *(ushort4*)(Wcat2 + (size_t)(elem >> 10) * 2048 + (elem & 1023)) = f4tob4(v);
    } else {
      const int k = elem - 524288;  // < 1048576
      const float4 v = *(const float4*)(W_enc + k);
      *(ushort4*)(EW2 + (size_t)(k >> 10) * 2048 + (k & 1023)) = f4tob4(v);
    }
  } else if (id < 2560) {
    const int b = id - 1536;
    const int j0 = (b >> 5) * 32, k0 = (b & 31) * 32;
    const int tx = tid & 31, ty = tid >> 5;
#pragma unroll
    for (int r = ty; r < 32; r += 8) t[r][tx] = W_dec[(size_t)(j0 + r) * 1024 + k0 + tx];
    __syncthreads();
#pragma unroll
    for (int r = ty; r < 32; r += 8)
      Wdt[(size_t)(k0 + r) * 1024 + j0 + tx] = __float2bfloat16(t[tx][r]);
  } else if (id < 4096) {
    const int o = id - 2560;  // < 1536
    // hidv[k] inline from biases (exact step-0 closed form)
    const float4 bd = *(const float4*)(b_dec + tid * 4);
    const float4 v1 = *(const float4*)(b_inp + tid * 4);
    const float4 v2 = *(const float4*)(b_rinp + tid * 4);
    const float4 v3 = *(const float4*)(b_ig + tid * 4);
    const float4 v4 = *(const float4*)(b_mig + tid * 4);
    const float4 v5 = *(const float4*)(b_rig + tid * 4);
    float4 hv;
    hv.x = bd.x + fsig(v1.x + v2.x) * fsig(v3.x + v4.x + v5.x);
    hv.y = bd.y + fsig(v1.y + v2.y) * fsig(v3.y + v4.y + v5.y);
    hv.z = bd.z + fsig(v1.z + v2.z) * fsig(v3.z + v4.z + v5.z);
    hv.w = bd.w + fsig(v1.w + v2.w) * fsig(v3.w + v4.w + v5.w);
    const float* row =
        (o < 512) ? (W_ho + (size_t)o * 1024) : (W_enc + (size_t)(o - 512) * 1024);
    const float4 a = *(const float4*)(row + tid * 4);
    const float s1 = wred(dot4(a, bd));   // . b_dec
    const float s2 = wred(dot4(a, hv));   // . hidv
    if ((tid & 63) == 0) {
      t[0][tid >> 6] = s1;
      t[1][tid >> 6] = s2;
    }
    __syncthreads();
    if (tid == 0) {
      const float d1 = t[0][0] + t[0][1] + t[0][2] + t[0][3];
      const float d2 = t[1][0] + t[1][1] + t[1][2] + t[1][3];
      if (o < 512) {
        vout[o] = d1;
        out_s[o] = d2;
      } else {
        const int e = o - 512;
        Web[e] = d1;
        const float wg = fsig(b_wg[e] + b_mwg[e] + b_rwg[e]);
        mem_s[e] = wg * ftanh(b_enc[e] + d2);  // mem0 == 0: no mem_s read
      }
    }
  } else {
    // ---- Wg7 cast: block handles 1024 elems of row j, fifth f ----
    const int b = id - 4096;  // < 5120
    const int j = b / 5, f = b - j * 5;
    const int col = f * 1024 + tid * 4;
    const float* src;
    int c0, stride;
    if (col < 512)       { src = Wri;  c0 = col;        stride = 512; }
    else if (col < 1536) { src = Wmig; c0 = col - 512;  stride = 1024; }
    else if (col < 2048) { src = Wrig; c0 = col - 1536; stride = 512; }
    else if (col < 3072) { src = Wmrg; c0 = col - 2048; stride = 1024; }
    else if (col < 3584) { src = Wrrg; c0 = col - 3072; stride = 512; }
    else if (col < 4608) { src = Wmwg; c0 = col - 3584; stride = 1024; }
    else                 { src = Wrwg; c0 = col - 4608; stride = 512; }
    const float4 v = *(const float4*)(src + (size_t)j * stride + c0);
    *(ushort4*)(Wg7 + (size_t)j * WG7_STRIDE + col) = f4tob4(v);
  }
}

// ================= recurrence stage 1: gates + per-launch rider blocks =================
// riders (blocks [0,riders)):
//   mode 0 (s=0, 384): P = bf16(Wcat2L.Wdt^T) -> Wcat2[:,1024:2048] (128 blocks);
//                      E = bf16(EW2L.Wdt^T)   -> EW2[:,1024:2048]   (256 blocks)
//   mode 1 (s=1, 2048): transpose input [512][4096] f32 -> Xb [4096][512] bf16
//   mode 2 (s=2, 1536): vectorized cast Wcat = bf16([Winp|Wig|Wrg])
// blocks [riders, riders+1024): per-row gates GEMV from bf16 Wg7 (row-packed)
__global__ __launch_bounds__(256) void gates_pe(
    const bf16* __restrict__ Wg7, const float* __restrict__ b_inp,
    const float* __restrict__ b_rinp, const float* __restrict__ b_ig,
    const float* __restrict__ b_mig, const float* __restrict__ b_rig,
    const float* __restrict__ b_rg, const float* __restrict__ b_mrg,
    const float* __restrict__ b_rrg, const float* __restrict__ b_wg,
    const float* __restrict__ b_mwg, const float* __restrict__ b_rwg,
    const float* __restrict__ out_s, const float* __restrict__ mem_s,
    float* __restrict__ rgm, float* __restrict__ h0v, float* __restrict__ wgv,
    const bf16* __restrict__ Wdt, bf16* __restrict__ Wcat2, bf16* __restrict__ EW2,
    const float* __restrict__ input, bf16* __restrict__ Xb,
    const float* __restrict__ W_inp, const float* __restrict__ W_ig,
    const float* __restrict__ W_rg, bf16* __restrict__ Wcat,
    int riders, int mode) {
  __shared__ char smem[32768];  // PE dbuf / transpose tile / GEMV reduction scratch
  const int tid = threadIdx.x;
  if ((int)blockIdx.x >= riders) {
    // ---- gates GEMV path (bf16 weights, one contiguous 10KB row) ----
    float(*red)[4] = (float(*)[4])smem;
    const int j = blockIdx.x - riders, lane = tid & 63, wave = tid >> 6;
    const float4 z = make_float4(0.f, 0.f, 0.f, 0.f);
    const float4 o4 = (tid < 128) ? *(const float4*)(out_s + tid * 4) : z;
    const float4 m4 = *(const float4*)(mem_s + tid * 4);
    const bf16* rowb = Wg7 + (size_t)j * WG7_STRIDE;
    float p[7];
    p[0] = (tid < 128) ? dot4(b2f4(*(const ushort4*)(rowb + tid * 4)), o4) : 0.f;
    p[1] = dot4(b2f4(*(const ushort4*)(rowb + 512 + tid * 4)), m4);
    p[2] = (tid < 128) ? dot4(b2f4(*(const ushort4*)(rowb + 1536 + tid * 4)), o4) : 0.f;
    p[3] = dot4(b2f4(*(const ushort4*)(rowb + 2048 + tid * 4)), m4);
    p[4] = (tid < 128) ? dot4(b2f4(*(const ushort4*)(rowb + 3072 + tid * 4)), o4) : 0.f;
    p[5] = dot4(b2f4(*(const ushort4*)(rowb + 3584 + tid * 4)), m4);
    p[6] = (tid < 128) ? dot4(b2f4(*(const ushort4*)(rowb + 4608 + tid * 4)), o4) : 0.f;
#pragma unroll
    for (int d = 0; d < 7; ++d) {
      float s = wred(p[d]);
      if (lane == 0) red[d][wave] = s;
    }
    __syncthreads();
    if (tid == 0) {
      float D[7];
#pragma unroll
      for (int d = 0; d < 7; ++d) D[d] = red[d][0] + red[d][1] + red[d][2] + red[d][3];
      const float abi = b_inp[j] + b_rinp[j] + D[0];
      const float aig = b_ig[j] + b_mig[j] + b_rig[j] + D[1] + D[2];
      const float arg = b_rg[j] + b_mrg[j] + b_rrg[j] + D[3] + D[4];
      const float awg = b_wg[j] + b_mwg[j] + b_rwg[j] + D[5] + D[6];
      rgm[j] = fsig(arg) * mem_s[j];
      h0v[j] = fsig(abi) * fsig(aig);
      wgv[j] = fsig(awg);
    }
    return;
  }
  if (mode == 1) {
    // ---- Xb transpose rider ----
    float(*t)[33] = (float(*)[33])smem;
    const int b = blockIdx.x;
    const int i0 = (b >> 7) * 32, b0 = (b & 127) * 32;
    const int tx = tid & 31, ty = tid >> 5;
#pragma unroll
    for (int r = ty; r < 32; r += 8) t[r][tx] = input[(size_t)(i0 + r) * 4096 + b0 + tx];
    __syncthreads();
#pragma unroll
    for (int r = ty; r < 32; r += 8)
      Xb[(size_t)(b0 + r) * 512 + i0 + tx] = __float2bfloat16(t[tx][r]);
    return;
  }
  if (mode == 2) {
    // ---- Wcat cast rider (vectorized) ----
    const int elem = ((int)blockIdx.x * 256 + tid) * 4;  // < 1572864
    float4 v;
    if (elem < 524288) v = *(const float4*)(W_inp + elem);
    else if (elem < 1048576) v = *(const float4*)(W_ig + elem - 524288);
    else v = *(const float4*)(W_rg + elem - 1048576);
    *(ushort4*)(Wcat + elem) = f4tob4(v);
    return;
  }
  // ---- mode 0: P/E GEMM rider, double-buffered; A/C in [.|.] 2048-stride buffers ----
  const int bi = blockIdx.x;
  const bf16* Ag;
  bf16* Cg;
  int m0, n0;
  if (bi < 128) {
    Ag = Wcat2; Cg = Wcat2 + 1024;  // P: A = Who rows (left half), C -> right half
    m0 = (bi >> 4) * 64; n0 = (bi & 15) * 64;
  } else {
    const int b2 = bi - 128;  // < 256
    Ag = EW2; Cg = EW2 + 1024;      // E: A = Wenc rows (left half), C -> right half
    m0 = (b2 >> 4) * 64; n0 = (b2 & 15) * 64;
  }
  const int wave = tid >> 6, lane = tid & 63;
  const int wm = wave >> 1, wn = wave & 1;
  f32x4 acc[2][2] = {};

  auto STAGE = [&](int kt, unsigned bofs) {
#pragma unroll
    for (int i = 0; i < 2; ++i) {
      const int ci = i * 256 + tid;
      const int row = ci >> 3, ck = (ci & 7) ^ (row & 7);
      const bf16* g = Ag + (size_t)(m0 + row) * 2048 + kt + ck * 8;
      const unsigned lofs =
          (unsigned)__builtin_amdgcn_readfirstlane(bofs + (i * 256 + wave * 64) * 16);
      __builtin_amdgcn_global_load_lds(
          (const __attribute__((address_space(1))) void*)g,
          (__attribute__((address_space(3))) void*)(smem + lofs), 16, 0, 0);
    }
#pragma unroll
    for (int i = 0; i < 2; ++i) {
      const int ci = i * 256 + tid;
      const int row = ci >> 3, ck = (ci & 7) ^ (row & 7);
      const bf16* g = Wdt + (size_t)(n0 + row) * 1024 + kt + ck * 8;
      const unsigned lofs =
          (unsigned)__builtin_amdgcn_readfirstlane(bofs + 8192 + (i * 256 + wave * 64) * 16);
      __builtin_amdgcn_global_load_lds(
          (const __attribute__((address_space(1))) void*)g,
          (__attribute__((address_space(3))) void*)(smem + lofs), 16, 0, 0);
    }
  };

  STAGE(0, 0);
  __syncthreads();
  unsigned cur = 0;
  for (int kt = 0; kt < 1024; kt += 64) {
    if (kt + 64 < 1024) STAGE(kt + 64, (cur ^ 1u) * 16384u);
#pragma unroll
    for (int ks = 0; ks < 2; ++ks) {
      const int ckk = ks * 4 + (lane >> 4);
      const unsigned cofs = cur * 16384u;
      s16x8 af[2];
#pragma unroll
      for (int i = 0; i < 2; ++i) {
        const int R = wm * 32 + i * 16 + (lane & 15);
        af[i] = *(const s16x8*)(smem + cofs + (R * 8 + (ckk ^ (R & 7))) * 16);
      }
#pragma unroll
      for (int j = 0; j < 2; ++j) {
        const int R = wn * 32 + j * 16 + (lane & 15);
        const s16x8 bfr = *(const s16x8*)(smem + cofs + 8192 + (R * 8 + (ckk ^ (R & 7))) * 16);
#pragma unroll
        for (int i = 0; i < 2; ++i)
          acc[i][j] = __builtin_amdgcn_mfma_f32_16x16x32_bf16(af[i], bfr, acc[i][j], 0, 0, 0);
      }
    }
    __syncthreads();  // drains vmcnt(0)+lgkmcnt(0): next-tile loads landed, all reads done
    cur ^= 1u;
  }
  const int mb = (lane >> 4) * 4, nb = lane & 15;
#pragma unroll
  for (int i = 0; i < 2; ++i) {
#pragma unroll
    for (int j = 0; j < 2; ++j) {
      const int col = n0 + wn * 32 + j * 16 + nb;
#pragma unroll
      for (int r = 0; r < 4; ++r) {
        const int rowg = m0 + wm * 32 + i * 16 + mb + r;
        Cg[(size_t)rowg * 2048 + col] = __float2bfloat16(acc[i][j][r]);
      }
    }
  }
}

// ================= recurrence stage 2: fused decode+update via E/P (unified rows) ========
// hid = b_dec + Wdec.rgm + h0v  (never materialized)
// mem' = (1-wg)mem + wg*tanh(b_enc + Web + Wenc.h0v + E.rgm)   [rows 0..1023, EW2 row]
// out' = vout + Who.h0v + P.rgm                                 [rows 1024..1535, Wcat2 row]
// Each block reads ONE contiguous 4KB bf16 row [left|right]; left cols pair h0v, right rgm.
__global__ void step_fuse(const bf16* __restrict__ EW2, const bf16* __restrict__ Wcat2,
                          const float* __restrict__ b_enc, const float* __restrict__ Web,
                          const float* __restrict__ vout, const float* __restrict__ rgm,
                          const float* __restrict__ h0v, const float* __restrict__ wgv,
                          float* __restrict__ mem_s, float* __restrict__ out_s) {
  __shared__ float red[4];
  const int id = blockIdx.x, tid = threadIdx.x;
  const bf16* row =
      (id < 1024) ? (EW2 + (size_t)id * 2048) : (Wcat2 + (size_t)(id - 1024) * 2048);
  const s16x8 v = *(const s16x8*)(row + tid * 8);
  const int c = (tid * 8) & 1023;
  const float* vec = (tid < 128) ? h0v : rgm;
  const float4 x0 = *(const float4*)(vec + c);
  const float4 x1 = *(const float4*)(vec + c + 4);
  const float s = wred(dot8(v, x0, x1));
  if ((tid & 63) == 0) red[tid >> 6] = s;
  __syncthreads();
  if (tid == 0) {
    const float d = red[0] + red[1] + red[2] + red[3];
    if (id < 1024) {
      const float wg = wgv[id];
      mem_s[id] = (1.0f - wg) * mem_s[id] + wg * ftanh(b_enc[id] + Web[id] + d);
    } else {
      out_s[id - 1024] = vout[id - 1024] + d;
    }
  }
}

// ================= step-4 constants: ccat = [c_bi|c_ig|c_rg] (bf16 Wg7 weights) =========
__global__ void final_consts(const bf16* __restrict__ Wg7, const float* __restrict__ b_inp,
                             const float* __restrict__ b_rinp, const float* __restrict__ b_ig,
                             const float* __restrict__ b_mig, const float* __restrict__ b_rig,
                             const float* __restrict__ b_rg, const float* __restrict__ b_mrg,
                             const float* __restrict__ b_rrg, const float* __restrict__ out_s,
                             const float* __restrict__ mem_s, float* __restrict__ ccat) {
  __shared__ float red[5][4];
  const int id = blockIdx.x, tid = threadIdx.x, lane = tid & 63, wave = tid >> 6;
  const float4 z = make_float4(0.f, 0.f, 0.f, 0.f);
  const float4 o4 = (tid < 128) ? *(const float4*)(out_s + tid * 4) : z;
  const float4 m4 = *(const float4*)(mem_s + tid * 4);
  const bf16* rowb = Wg7 + (size_t)id * WG7_STRIDE;
  float p[5];
  p[0] = (tid < 128) ? dot4(b2f4(*(const ushort4*)(rowb + tid * 4)), o4) : 0.f;
  p[1] = dot4(b2f4(*(const ushort4*)(rowb + 512 + tid * 4)), m4);
  p[2] = (tid < 128) ? dot4(b2f4(*(const ushort4*)(rowb + 1536 + tid * 4)), o4) : 0.f;
  p[3] = dot4(b2f4(*(const ushort4*)(rowb + 2048 + tid * 4)), m4);
  p[4] = (tid < 128) ? dot4(b2f4(*(const ushort4*)(rowb + 3072 + tid * 4)), o4) : 0.f;
#pragma unroll
  for (int d = 0; d < 5; ++d) {
    float s = wred(p[d]);
    if (lane == 0) red[d][wave] = s;
  }
  __syncthreads();
  if (tid == 0) {
    float D[5];
#pragma unroll
    for (int d = 0; d < 5; ++d) D[d] = red[d][0] + red[d][1] + red[d][2] + red[d][3];
    ccat[id] = b_inp[id] + b_rinp[id] + D[0];
    ccat[1024 + id] = b_ig[id] + b_mig[id] + b_rig[id] + D[1] + D[2];
    ccat[2048 + id] = b_rg[id] + b_mrg[id] + b_rrg[id] + D[3] + D[4];
  }
}

// ================= gate GEMM: NG=3, 64x64 tile, fused sigmoid + H0 product =================
// Measured-best form: single-buffered BK=64 @4 blocks/CU (dbuf@2blk -5us R5; BK32 null R7).
// Epilogue folds mem3 into rg (rg*mem3 -> Hcat right). XCD swizzle for L2 locality.
__global__ __launch_bounds__(256, 4) void gemm_gates(const bf16* __restrict__ A,
                                                     const bf16* __restrict__ Wcat,
                                                     const float* __restrict__ ccat,
                                                     const float* __restrict__ mem_s,
                                                     bf16* __restrict__ Hcat) {
  __shared__ char smem[32768];  // A tile 8KB @0; B_g tile 8KB @ 8192+g*8192
  const int tid = threadIdx.x, wave = tid >> 6, lane = tid & 63;
  const int wm = wave >> 1, wn = wave & 1;
  const int swz = (blockIdx.x & 7) * 128 + (blockIdx.x >> 3);
  const int m0 = (swz >> 4) * 64, n0 = (swz & 15) * 64;
  f32x4 acc[3][2][2] = {};

  for (int kt = 0; kt < 512; kt += 64) {
    __syncthreads();
#pragma unroll
    for (int i = 0; i < 2; ++i) {
      const int ci = i * 256 + tid;
      const int row = ci >> 3, ck = (ci & 7) ^ (row & 7);
      const bf16* g = A + (size_t)(m0 + row) * 512 + kt + ck * 8;
      const unsigned lofs = (unsigned)__builtin_amdgcn_readfirstlane((i * 256 + wave * 64) * 16);
      __builtin_amdgcn_global_load_lds(
          (const __attribute__((address_space(1))) void*)g,
          (__attribute__((address_space(3))) void*)(smem + lofs), 16, 0, 0);
    }
#pragma unroll
    for (int gI = 0; gI < 3; ++gI) {
      const bf16* Bp = Wcat + gI * 524288;
#pragma unroll
      for (int i = 0; i < 2; ++i) {
        const int ci = i * 256 + tid;
        const int row = ci >> 3, ck = (ci & 7) ^ (row & 7);
        const bf16* g = Bp + (size_t)(n0 + row) * 512 + kt + ck * 8;
        const unsigned lofs = (unsigned)__builtin_amdgcn_readfirstlane(
            8192 + gI * 8192 + (i * 256 + wave * 64) * 16);
        __builtin_amdgcn_global_load_lds(
            (const __attribute__((address_space(1))) void*)g,
            (__attribute__((address_space(3))) void*)(smem + lofs), 16, 0, 0);
      }
    }
    __syncthreads();

#pragma unroll
    for (int ks = 0; ks < 2; ++ks) {
      const int ckk = ks * 4 + (lane >> 4);
      s16x8 af[2];
#pragma unroll
      for (int i = 0; i < 2; ++i) {
        const int R = wm * 32 + i * 16 + (lane & 15);
        af[i] = *(const s16x8*)(smem + (R * 8 + (ckk ^ (R & 7))) * 16);
      }
#pragma unroll
      for (int gI = 0; gI < 3; ++gI) {
#pragma unroll
        for (int j = 0; j < 2; ++j) {
          const int R = wn * 32 + j * 16 + (lane & 15);
          const s16x8 bfr =
              *(const s16x8*)(smem + 8192 + gI * 8192 + (R * 8 + (ckk ^ (R & 7))) * 16);
#pragma unroll
          for (int i = 0; i < 2; ++i)
            acc[gI][i][j] =
                __builtin_amdgcn_mfma_f32_16x16x32_bf16(af[i], bfr, acc[gI][i][j], 0, 0, 0);
        }
      }
    }
  }

  // epilogue: fast sigmoid (+mem3 fold on rg) -> LDS repack (stride 80) -> 16B stores
  __syncthreads();
  bf16* sm = (bf16*)smem;          // H0 tile [64][80]
  bf16* sr = (bf16*)smem + 5120;   // RG*mem3 tile [64][80]
  const int mb = (lane >> 4) * 4, nb = lane & 15;
#pragma unroll
  for (int i = 0; i < 2; ++i) {
#pragma unroll
    for (int j = 0; j < 2; ++j) {
      const int colL = wn * 32 + j * 16 + nb;
      const int jg = n0 + colL;
      const float c0 = ccat[jg], c1 = ccat[1024 + jg], c2 = ccat[2048 + jg];
      const float m3 = mem_s[jg];
#pragma unroll
      for (int r = 0; r < 4; ++r) {
        const int rowL = wm * 32 + i * 16 + mb + r;
        const float h = fsig(acc[0][i][j][r] + c0) * fsig(acc[1][i][j][r] + c1);
        const float rg = fsig(acc[2][i][j][r] + c2) * m3;
        sm[rowL * 80 + colL] = __float2bfloat16(h);
        sr[rowL * 80 + colL] = __float2bfloat16(rg);
      }
    }
  }
  __syncthreads();
#pragma unroll
  for (int pp = 0; pp < 2; ++pp) {  // 64 rows x 8 chunks = 512 chunks per tile
    const int c = pp * 256 + tid;
    const int row = c >> 3, cc = c & 7;
    const s16x8 v0 = *(const s16x8*)(sm + row * 80 + cc * 8);
    const s16x8 v1 = *(const s16x8*)(sr + row * 80 + cc * 8);
    *(s16x8*)(Hcat + (size_t)(m0 + row) * 2048 + n0 + cc * 8) = v0;
    *(s16x8*)(Hcat + (size_t)(m0 + row) * 2048 + 1024 + n0 + cc * 8) = v1;
  }
}

// ================= out GEMM: 32x64 tile, K=2048, dbuf, 1024 blocks @4/CU =================
// R10 hypothesis: 64x64 grid was 512 blocks = 2 blocks/CU (half-subscribed). 32x64 tiles
// double the grid to 1024 = 4/CU for latency hiding; cost +128MB L2-resident A re-reads.
// LDS: dbuf x {A 4KB + B 8KB} = 24KB. Waves: 2x2 grid of 16x32 outputs (acc f32x4[2]).
// XCD swizzle: grid 128(m) x 8(n); each XCD owns 16 m-panels x all n (A 2MB + B 2MB in L2).
__global__ __launch_bounds__(256, 4) void gemm_out(const bf16* __restrict__ A,
                                                   const bf16* __restrict__ Bp,
                                                   const float* __restrict__ vout,
                                                   float* __restrict__ outF) {
  __shared__ char smem[24576];  // dbuf: buf {A 4KB @0, B 8KB @4096}, stride 12288
  const int tid = threadIdx.x, wave = tid >> 6, lane = tid & 63;
  const int wm = wave >> 1, wn = wave & 1;  // 2x2 waves over 32x64 tile
  const int swz = (blockIdx.x & 7) * 128 + (blockIdx.x >> 3);
  const int m0 = (swz >> 3) * 32, n0 = (swz & 7) * 64;
  f32x4 acc[2] = {};

  auto STAGE = [&](int kt, unsigned bofs) {
    {  // A: 32 rows x 64k x 2B = 4KB, one 256-thread pass
      const int row = tid >> 3, ck = (tid & 7) ^ (row & 7);
      const bf16* g = A + (size_t)(m0 + row) * 2048 + kt + ck * 8;
      const unsigned lofs = (unsigned)__builtin_amdgcn_readfirstlane(bofs + wave * 1024u);
      __builtin_amdgcn_global_load_lds(
          (const __attribute__((address_space(1))) void*)g,
          (__attribute__((address_space(3))) void*)(smem + lofs), 16, 0, 0);
    }
#pragma unroll
    for (int i = 0; i < 2; ++i) {  // B: 64 rows x 64k = 8KB, two passes
      const int ci = i * 256 + tid;
      const int row = ci >> 3, ck = (ci & 7) ^ (row & 7);
      const bf16* g = Bp + (size_t)(n0 + row) * 2048 + kt + ck * 8;
      const unsigned lofs =
          (unsigned)__builtin_amdgcn_readfirstlane(bofs + 4096 + (i * 256 + wave * 64) * 16);
      __builtin_amdgcn_global_load_lds(
          (const __attribute__((address_space(1))) void*)g,
          (__attribute__((address_space(3))) void*)(smem + lofs), 16, 0, 0);
    }
  };

  STAGE(0, 0);
  __syncthreads();
  unsigned cur = 0;
  for (int kt = 0; kt < 2048; kt += 64) {
    if (kt + 64 < 2048) STAGE(kt + 64, (cur ^ 1u) * 12288u);
#pragma unroll
    for (int ks = 0; ks < 2; ++ks) {
      const int ckk = ks * 4 + (lane >> 4);
      const unsigned cofs = cur * 12288u;
      const int Ra = wm * 16 + (lane & 15);
      const s16x8 af = *(const s16x8*)(smem + cofs + (Ra * 8 + (ckk ^ (Ra & 7))) * 16);
#pragma unroll
      for (int j = 0; j < 2; ++j) {
        const int R = wn * 32 + j * 16 + (lane & 15);
        const s16x8 bfr = *(const s16x8*)(smem + cofs + 4096 + (R * 8 + (ckk ^ (R & 7))) * 16);
        acc[j] = __builtin_amdgcn_mfma_f32_16x16x32_bf16(af, bfr, acc[j], 0, 0, 0);
      }
    }
    __syncthreads();  // drains vmcnt(0)+lgkmcnt(0): next-tile loads landed, all reads done
    cur ^= 1u;
  }

  const int mb = (lane >> 4) * 4, nb = lane & 15;
#pragma unroll
  for (int j = 0; j < 2; ++j) {
    const int col = n0 + wn * 32 + j * 16 + nb;
#pragma unroll
    for (int r = 0; r < 4; ++r) {
      const int rowg = m0 + wm * 16 + mb + r;
      outF[(size_t)rowg * 512 + col] = acc[j][r] + vout[col];
    }
  }
}

extern "C" void kernel_launch(void* const* d_in, const int* in_sizes, int n_in, void* d_out,
                              int out_size, void* d_ws, size_t ws_size, hipStream_t stream) {
  const float* input  = (const float*)d_in[0];
  const float* W_ig   = (const float*)d_in[1];  const float* b_ig   = (const float*)d_in[2];
  const float* W_rig  = (const float*)d_in[3];  const float* b_rig  = (const float*)d_in[4];
  const float* W_mig  = (const float*)d_in[5];  const float* b_mig  = (const float*)d_in[6];
  const float* W_inp  = (const float*)d_in[7];  const float* b_inp  = (const float*)d_in[8];
  const float* W_rinp = (const float*)d_in[9];  const float* b_rinp = (const float*)d_in[10];
  const float* W_rg   = (const float*)d_in[11]; const float* b_rg   = (const float*)d_in[12];
  const float* W_rrg  = (const float*)d_in[13]; const float* b_rrg  = (const float*)d_in[14];
  const float* W_mrg  = (const float*)d_in[15]; const float* b_mrg  = (const float*)d_in[16];
  const float* W_dec  = (const float*)d_in[17]; const float* b_dec  = (const float*)d_in[18];
  const float* W_wg   = (const float*)d_in[19]; const float* b_wg   = (const float*)d_in[20];
  const float* W_rwg  = (const float*)d_in[21]; const float* b_rwg  = (const float*)d_in[22];
  const float* W_mwg  = (const float*)d_in[23]; const float* b_mwg  = (const float*)d_in[24];
  const float* W_enc  = (const float*)d_in[25]; const float* b_enc  = (const float*)d_in[26];
  const float* W_ho   = (const float*)d_in[27];
  (void)W_wg;  // input-side write gate weight: dead (x=0 in steps 0-3; step-4 write gate dead)

  char* ws = (char*)d_ws;
  float* out_s = (float*)(ws + 0);
  float* mem_s = (float*)(ws + 4096);
  float* rgm   = (float*)(ws + 8192);
  float* h0v   = (float*)(ws + 12288);
  float* wgv   = (float*)(ws + 16384);
  float* ccat  = (float*)(ws + 24576);   // 3072 f32
  float* vout  = (float*)(ws + 40960);   // 512 f32
  float* Web   = (float*)(ws + 45056);   // 1024 f32 (Wenc . b_dec)
  bf16* Xb     = (bf16*)(ws + 2162688);                // [4096][512] (4MB)
  bf16* Wcat   = (bf16*)(ws + 6356992);                // [3072][512] (3MB)
  bf16* Wcat2  = (bf16*)(ws + 10551296);               // [512][2048] = [Who | P] (2MB)
  bf16* Wdt    = (bf16*)(ws + 12648448);               // [1024][1024] (2MB)
  bf16* Hcat   = (bf16*)(ws + 14745600);               // [4096][2048] (16MB)
  bf16* EW2    = (bf16*)(ws + 31522816);               // [1024][2048] = [Wenc | E] (4MB)
  bf16* Wg7    = (bf16*)(ws + 37814272);               // [1024][5120] bf16 (10.5MB)

  // setup: Who/Wenc casts + Wdt transpose + merged GEMVs + step-0 update + Wg7 cast
  setup<<<9216, 256, 0, stream>>>(W_ho, W_dec, W_enc,
                                  W_rinp, W_mig, W_rig, W_mrg, W_rrg, W_mwg, W_rwg,
                                  b_inp, b_rinp, b_ig, b_mig, b_rig, b_wg, b_mwg, b_rwg,
                                  b_dec, b_enc, Wcat2, Wdt, EW2, out_s, mem_s, vout, Web, Wg7);

  // steps 1..3: gates + riders {s0: P/E GEMM, s1: Xb transpose, s2: Wcat cast}
  for (int s = 0; s < 3; ++s) {
    const int riders = (s == 0) ? 384 : (s == 1) ? 2048 : 1536;
    const int mode = s;
    gates_pe<<<1024 + riders, 256, 0, stream>>>(
        Wg7, b_inp, b_rinp, b_ig, b_mig, b_rig, b_rg, b_mrg, b_rrg, b_wg, b_mwg, b_rwg,
        out_s, mem_s, rgm, h0v, wgv, Wdt, Wcat2, EW2, input, Xb, W_inp, W_ig, W_rg, Wcat,
        riders, mode);
    step_fuse<<<1536, 256, 0, stream>>>(EW2, Wcat2, b_enc, Web, vout, rgm, h0v, wgv, mem_s,
                                        out_s);
  }

  // step-4 constants (ccat) only — M1 scaling folded into gemm_gates epilogue
  final_consts<<<1024, 256, 0, stream>>>(Wg7, b_inp, b_rinp, b_ig, b_mig, b_rig, b_rg, b_mrg,
                                         b_rrg, out_s, mem_s, ccat);

  // gates: Hcat = [sig*sig | sig*mem3] of Xb . [Wi|Wg|Wr]^T + ccat
  gemm_gates<<<1024, 256, 0, stream>>>(Xb, Wcat, ccat, mem_s, Hcat);

  // out = [H0|rg*mem3] . [Who|P]^T + vout  (direct store, 32x64 tiles @4 blocks/CU)
  gemm_out<<<1024, 256, 0, stream>>>(Hcat, Wcat2, vout, (float*)d_out);
}

// Round 11
// 212.338 us; speedup vs baseline: 1.0172x; 1.0172x over previous
//
#include <hip/hip_runtime.h>
#include <hip/hip_bf16.h>
#include <math.h>

typedef __hip_bfloat16 bf16;
typedef __attribute__((ext_vector_type(8))) short s16x8;   // 8 bf16 (4 VGPRs)
typedef __attribute__((ext_vector_type(4))) float f32x4;

__device__ __forceinline__ float fsig(float x) {
  return __builtin_amdgcn_rcpf(1.0f + __expf(-x));
}
__device__ __forceinline__ float ftanh(float x) { return 2.0f * fsig(2.0f * x) - 1.0f; }
__device__ __forceinline__ float dot4(float4 a, float4 b) {
  return a.x * b.x + a.y * b.y + a.z * b.z + a.w * b.w;
}
__device__ __forceinline__ float wred(float s) {
#pragma unroll
  for (int off = 32; off > 0; off >>= 1) s += __shfl_down(s, off, 64);
  return s;
}
__device__ __forceinline__ float b2f(unsigned short u) {
  return __uint_as_float((unsigned)u << 16);
}
__device__ __forceinline__ float4 b2f4(ushort4 u) {
  return make_float4(b2f(u.x), b2f(u.y), b2f(u.z), b2f(u.w));
}
__device__ __forceinline__ float dot8(s16x8 v, float4 a, float4 b) {
  return b2f((unsigned short)v[0]) * a.x + b2f((unsigned short)v[1]) * a.y +
         b2f((unsigned short)v[2]) * a.z + b2f((unsigned short)v[3]) * a.w +
         b2f((unsigned short)v[4]) * b.x + b2f((unsigned short)v[5]) * b.y +
         b2f((unsigned short)v[6]) * b.z + b2f((unsigned short)v[7]) * b.w;
}
__device__ __forceinline__ ushort4 f4tob4(float4 v) {
  ushort4 u;
  u.x = __bfloat16_as_ushort(__float2bfloat16(v.x));
  u.y = __bfloat16_as_ushort(__float2bfloat16(v.y));
  u.z = __bfloat16_as_ushort(__float2bfloat16(v.z));
  u.w = __bfloat16_as_ushort(__float2bfloat16(v.w));
  return u;
}

// Wg7 row layout (bf16, 5120 per row): [Wri 0 | Wmig 512 | Wrig 1536 | Wmrg 2048 |
//                                       Wrrg 3072 | Wmwg 3584 | Wrwg 4608]
#define WG7_STRIDE 5120

// ================= setup (bulk Xb/Wcat staging moved to gates_pe riders) =================
// [0,1536):     vectorized casts: Wcat2 left = bf16(W_ho); EW2 left = bf16(W_enc)
// [1536,2560):  Wdt[k][j] = bf16(W_dec[j][k])
// [2560,4096):  merged GEMV: Who rows o<512 -> vout[o]=Who.b_dec, out_s[o]=Who.hidv
//               Wenc rows e=o-512 -> Web[e]=Wenc.b_dec, mem_s[e]=wg*tanh(b_enc+Wenc.hidv)
//               (hidv = step-0 closed form from biases; mem0=0 so no mem read)
// [4096,9216):  cast 7 gate-weight matrices into row-packed bf16 Wg7[1024][5120]
__global__ void setup(const float* __restrict__ W_ho, const float* __restrict__ W_dec,
                      const float* __restrict__ W_enc,
                      const float* __restrict__ Wri, const float* __restrict__ Wmig,
                      const float* __restrict__ Wrig, const float* __restrict__ Wmrg,
                      const float* __restrict__ Wrrg, const float* __restrict__ Wmwg,
                      const float* __restrict__ Wrwg,
                      const float* __restrict__ b_inp, const float* __restrict__ b_rinp,
                      const float* __restrict__ b_ig, const float* __restrict__ b_mig,
                      const float* __restrict__ b_rig, const float* __restrict__ b_wg,
                      const float* __restrict__ b_mwg, const float* __restrict__ b_rwg,
                      const float* __restrict__ b_dec, const float* __restrict__ b_enc,
                      bf16* __restrict__ Wcat2, bf16* __restrict__ Wdt,
                      bf16* __restrict__ EW2,
                      float* __restrict__ out_s, float* __restrict__ mem_s,
                      float* __restrict__ vout, float* __restrict__ Web,
                      bf16* __restrict__ Wg7) {
  __shared__ float t[32][33];
  const int id = blockIdx.x, tid = threadIdx.x;
  if (id < 1536) {
    const int elem = (id * 256 + tid) * 4;  // < 1572864
    if (elem < 524288) {
      const float4 v = *(const float4*)(W_ho + elem);
      *(ushort4*)(Wcat2 + (size_t)(elem >> 10) * 2048 + (elem & 1023)) = f4tob4(v);
    } else {
      const int k = elem - 524288;  // < 1048576
      const float4 v = *(const float4*)(W_enc + k);
      *(ushort4*)(EW2 + (size_t)(k >> 10) * 2048 + (k & 1023)) = f4tob4(v);
    }
  } else if (id < 2560) {
    const int b = id - 1536;
    const int j0 = (b >> 5) * 32, k0 = (b & 31) * 32;
    const int tx = tid & 31, ty = tid >> 5;
#pragma unroll
    for (int r = ty; r < 32; r += 8) t[r][tx] = W_dec[(size_t)(j0 + r) * 1024 + k0 + tx];
    __syncthreads();
#pragma unroll
    for (int r = ty; r < 32; r += 8)
      Wdt[(size_t)(k0 + r) * 1024 + j0 + tx] = __float2bfloat16(t[tx][r]);
  } else if (id < 4096) {
    const int o = id - 2560;  // < 1536
    // hidv[k] inline from biases (exact step-0 closed form)
    const float4 bd = *(const float4*)(b_dec + tid * 4);
    const float4 v1 = *(const float4*)(b_inp + tid * 4);
    const float4 v2 = *(const float4*)(b_rinp + tid * 4);
    const float4 v3 = *(const float4*)(b_ig + tid * 4);
    const float4 v4 = *(const float4*)(b_mig + tid * 4);
    const float4 v5 = *(const float4*)(b_rig + tid * 4);
    float4 hv;
    hv.x = bd.x + fsig(v1.x + v2.x) * fsig(v3.x + v4.x + v5.x);
    hv.y = bd.y + fsig(v1.y + v2.y) * fsig(v3.y + v4.y + v5.y);
    hv.z = bd.z + fsig(v1.z + v2.z) * fsig(v3.z + v4.z + v5.z);
    hv.w = bd.w + fsig(v1.w + v2.w) * fsig(v3.w + v4.w + v5.w);
    const float* row =
        (o < 512) ? (W_ho + (size_t)o * 1024) : (W_enc + (size_t)(o - 512) * 1024);
    const float4 a = *(const float4*)(row + tid * 4);
    const float s1 = wred(dot4(a, bd));   // . b_dec
    const float s2 = wred(dot4(a, hv));   // . hidv
    if ((tid & 63) == 0) {
      t[0][tid >> 6] = s1;
      t[1][tid >> 6] = s2;
    }
    __syncthreads();
    if (tid == 0) {
      const float d1 = t[0][0] + t[0][1] + t[0][2] + t[0][3];
      const float d2 = t[1][0] + t[1][1] + t[1][2] + t[1][3];
      if (o < 512) {
        vout[o] = d1;
        out_s[o] = d2;
      } else {
        const int e = o - 512;
        Web[e] = d1;
        const float wg = fsig(b_wg[e] + b_mwg[e] + b_rwg[e]);
        mem_s[e] = wg * ftanh(b_enc[e] + d2);  // mem0 == 0: no mem_s read
      }
    }
  } else {
    // ---- Wg7 cast: block handles 1024 elems of row j, fifth f ----
    const int b = id - 4096;  // < 5120
    const int j = b / 5, f = b - j * 5;
    const int col = f * 1024 + tid * 4;
    const float* src;
    int c0, stride;
    if (col < 512)       { src = Wri;  c0 = col;        stride = 512; }
    else if (col < 1536) { src = Wmig; c0 = col - 512;  stride = 1024; }
    else if (col < 2048) { src = Wrig; c0 = col - 1536; stride = 512; }
    else if (col < 3072) { src = Wmrg; c0 = col - 2048; stride = 1024; }
    else if (col < 3584) { src = Wrrg; c0 = col - 3072; stride = 512; }
    else if (col < 4608) { src = Wmwg; c0 = col - 3584; stride = 1024; }
    else                 { src = Wrwg; c0 = col - 4608; stride = 512; }
    const float4 v = *(const float4*)(src + (size_t)j * stride + c0);
    *(ushort4*)(Wg7 + (size_t)j * WG7_STRIDE + col) = f4tob4(v);
  }
}

// ================= recurrence stage 1: gates + per-launch rider blocks =================
// riders (blocks [0,riders)):
//   mode 0 (s=0, 384): P = bf16(Wcat2L.Wdt^T) -> Wcat2[:,1024:2048] (128 blocks);
//                      E = bf16(EW2L.Wdt^T)   -> EW2[:,1024:2048]   (256 blocks)
//   mode 1 (s=1, 2048): transpose input [512][4096] f32 -> Xb [4096][512] bf16
//   mode 2 (s=2, 1536): vectorized cast Wcat = bf16([Winp|Wig|Wrg])
// blocks [riders, riders+1024): per-row gates GEMV from bf16 Wg7 (row-packed)
__global__ __launch_bounds__(256) void gates_pe(
    const bf16* __restrict__ Wg7, const float* __restrict__ b_inp,
    const float* __restrict__ b_rinp, const float* __restrict__ b_ig,
    const float* __restrict__ b_mig, const float* __restrict__ b_rig,
    const float* __restrict__ b_rg, const float* __restrict__ b_mrg,
    const float* __restrict__ b_rrg, const float* __restrict__ b_wg,
    const float* __restrict__ b_mwg, const float* __restrict__ b_rwg,
    const float* __restrict__ out_s, const float* __restrict__ mem_s,
    float* __restrict__ rgm, float* __restrict__ h0v, float* __restrict__ wgv,
    const bf16* __restrict__ Wdt, bf16* __restrict__ Wcat2, bf16* __restrict__ EW2,
    const float* __restrict__ input, bf16* __restrict__ Xb,
    const float* __restrict__ W_inp, const float* __restrict__ W_ig,
    const float* __restrict__ W_rg, bf16* __restrict__ Wcat,
    int riders, int mode) {
  __shared__ char smem[32768];  // PE dbuf / transpose tile / GEMV reduction scratch
  const int tid = threadIdx.x;
  if ((int)blockIdx.x >= riders) {
    // ---- gates GEMV path (bf16 weights, one contiguous 10KB row) ----
    float(*red)[4] = (float(*)[4])smem;
    const int j = blockIdx.x - riders, lane = tid & 63, wave = tid >> 6;
    const float4 z = make_float4(0.f, 0.f, 0.f, 0.f);
    const float4 o4 = (tid < 128) ? *(const float4*)(out_s + tid * 4) : z;
    const float4 m4 = *(const float4*)(mem_s + tid * 4);
    const bf16* rowb = Wg7 + (size_t)j * WG7_STRIDE;
    float p[7];
    p[0] = (tid < 128) ? dot4(b2f4(*(const ushort4*)(rowb + tid * 4)), o4) : 0.f;
    p[1] = dot4(b2f4(*(const ushort4*)(rowb + 512 + tid * 4)), m4);
    p[2] = (tid < 128) ? dot4(b2f4(*(const ushort4*)(rowb + 1536 + tid * 4)), o4) : 0.f;
    p[3] = dot4(b2f4(*(const ushort4*)(rowb + 2048 + tid * 4)), m4);
    p[4] = (tid < 128) ? dot4(b2f4(*(const ushort4*)(rowb + 3072 + tid * 4)), o4) : 0.f;
    p[5] = dot4(b2f4(*(const ushort4*)(rowb + 3584 + tid * 4)), m4);
    p[6] = (tid < 128) ? dot4(b2f4(*(const ushort4*)(rowb + 4608 + tid * 4)), o4) : 0.f;
#pragma unroll
    for (int d = 0; d < 7; ++d) {
      float s = wred(p[d]);
      if (lane == 0) red[d][wave] = s;
    }
    __syncthreads();
    if (tid == 0) {
      float D[7];
#pragma unroll
      for (int d = 0; d < 7; ++d) D[d] = red[d][0] + red[d][1] + red[d][2] + red[d][3];
      const float abi = b_inp[j] + b_rinp[j] + D[0];
      const float aig = b_ig[j] + b_mig[j] + b_rig[j] + D[1] + D[2];
      const float arg = b_rg[j] + b_mrg[j] + b_rrg[j] + D[3] + D[4];
      const float awg = b_wg[j] + b_mwg[j] + b_rwg[j] + D[5] + D[6];
      rgm[j] = fsig(arg) * mem_s[j];
      h0v[j] = fsig(abi) * fsig(aig);
      wgv[j] = fsig(awg);
    }
    return;
  }
  if (mode == 1) {
    // ---- Xb transpose rider ----
    float(*t)[33] = (float(*)[33])smem;
    const int b = blockIdx.x;
    const int i0 = (b >> 7) * 32, b0 = (b & 127) * 32;
    const int tx = tid & 31, ty = tid >> 5;
#pragma unroll
    for (int r = ty; r < 32; r += 8) t[r][tx] = input[(size_t)(i0 + r) * 4096 + b0 + tx];
    __syncthreads();
#pragma unroll
    for (int r = ty; r < 32; r += 8)
      Xb[(size_t)(b0 + r) * 512 + i0 + tx] = __float2bfloat16(t[tx][r]);
    return;
  }
  if (mode == 2) {
    // ---- Wcat cast rider (vectorized) ----
    const int elem = ((int)blockIdx.x * 256 + tid) * 4;  // < 1572864
    float4 v;
    if (elem < 524288) v = *(const float4*)(W_inp + elem);
    else if (elem < 1048576) v = *(const float4*)(W_ig + elem - 524288);
    else v = *(const float4*)(W_rg + elem - 1048576);
    *(ushort4*)(Wcat + elem) = f4tob4(v);
    return;
  }
  // ---- mode 0: P/E GEMM rider, double-buffered; A/C in [.|.] 2048-stride buffers ----
  const int bi = blockIdx.x;
  const bf16* Ag;
  bf16* Cg;
  int m0, n0;
  if (bi < 128) {
    Ag = Wcat2; Cg = Wcat2 + 1024;  // P: A = Who rows (left half), C -> right half
    m0 = (bi >> 4) * 64; n0 = (bi & 15) * 64;
  } else {
    const int b2 = bi - 128;  // < 256
    Ag = EW2; Cg = EW2 + 1024;      // E: A = Wenc rows (left half), C -> right half
    m0 = (b2 >> 4) * 64; n0 = (b2 & 15) * 64;
  }
  const int wave = tid >> 6, lane = tid & 63;
  const int wm = wave >> 1, wn = wave & 1;
  f32x4 acc[2][2] = {};

  auto STAGE = [&](int kt, unsigned bofs) {
#pragma unroll
    for (int i = 0; i < 2; ++i) {
      const int ci = i * 256 + tid;
      const int row = ci >> 3, ck = (ci & 7) ^ (row & 7);
      const bf16* g = Ag + (size_t)(m0 + row) * 2048 + kt + ck * 8;
      const unsigned lofs =
          (unsigned)__builtin_amdgcn_readfirstlane(bofs + (i * 256 + wave * 64) * 16);
      __builtin_amdgcn_global_load_lds(
          (const __attribute__((address_space(1))) void*)g,
          (__attribute__((address_space(3))) void*)(smem + lofs), 16, 0, 0);
    }
#pragma unroll
    for (int i = 0; i < 2; ++i) {
      const int ci = i * 256 + tid;
      const int row = ci >> 3, ck = (ci & 7) ^ (row & 7);
      const bf16* g = Wdt + (size_t)(n0 + row) * 1024 + kt + ck * 8;
      const unsigned lofs =
          (unsigned)__builtin_amdgcn_readfirstlane(bofs + 8192 + (i * 256 + wave * 64) * 16);
      __builtin_amdgcn_global_load_lds(
          (const __attribute__((address_space(1))) void*)g,
          (__attribute__((address_space(3))) void*)(smem + lofs), 16, 0, 0);
    }
  };

  STAGE(0, 0);
  __syncthreads();
  unsigned cur = 0;
  for (int kt = 0; kt < 1024; kt += 64) {
    if (kt + 64 < 1024) STAGE(kt + 64, (cur ^ 1u) * 16384u);
#pragma unroll
    for (int ks = 0; ks < 2; ++ks) {
      const int ckk = ks * 4 + (lane >> 4);
      const unsigned cofs = cur * 16384u;
      s16x8 af[2];
#pragma unroll
      for (int i = 0; i < 2; ++i) {
        const int R = wm * 32 + i * 16 + (lane & 15);
        af[i] = *(const s16x8*)(smem + cofs + (R * 8 + (ckk ^ (R & 7))) * 16);
      }
#pragma unroll
      for (int j = 0; j < 2; ++j) {
        const int R = wn * 32 + j * 16 + (lane & 15);
        const s16x8 bfr = *(const s16x8*)(smem + cofs + 8192 + (R * 8 + (ckk ^ (R & 7))) * 16);
#pragma unroll
        for (int i = 0; i < 2; ++i)
          acc[i][j] = __builtin_amdgcn_mfma_f32_16x16x32_bf16(af[i], bfr, acc[i][j], 0, 0, 0);
      }
    }
    __syncthreads();  // drains vmcnt(0)+lgkmcnt(0): next-tile loads landed, all reads done
    cur ^= 1u;
  }
  const int mb = (lane >> 4) * 4, nb = lane & 15;
#pragma unroll
  for (int i = 0; i < 2; ++i) {
#pragma unroll
    for (int j = 0; j < 2; ++j) {
      const int col = n0 + wn * 32 + j * 16 + nb;
#pragma unroll
      for (int r = 0; r < 4; ++r) {
        const int rowg = m0 + wm * 32 + i * 16 + mb + r;
        Cg[(size_t)rowg * 2048 + col] = __float2bfloat16(acc[i][j][r]);
      }
    }
  }
}

// ================= recurrence stage 2: fused decode+update via E/P (unified rows) ========
// hid = b_dec + Wdec.rgm + h0v  (never materialized)
// mem' = (1-wg)mem + wg*tanh(b_enc + Web + Wenc.h0v + E.rgm)   [rows 0..1023, EW2 row]
// out' = vout + Who.h0v + P.rgm                                 [rows 1024..1535, Wcat2 row]
// Each block reads ONE contiguous 4KB bf16 row [left|right]; left cols pair h0v, right rgm.
__global__ void step_fuse(const bf16* __restrict__ EW2, const bf16* __restrict__ Wcat2,
                          const float* __restrict__ b_enc, const float* __restrict__ Web,
                          const float* __restrict__ vout, const float* __restrict__ rgm,
                          const float* __restrict__ h0v, const float* __restrict__ wgv,
                          float* __restrict__ mem_s, float* __restrict__ out_s) {
  __shared__ float red[4];
  const int id = blockIdx.x, tid = threadIdx.x;
  const bf16* row =
      (id < 1024) ? (EW2 + (size_t)id * 2048) : (Wcat2 + (size_t)(id - 1024) * 2048);
  const s16x8 v = *(const s16x8*)(row + tid * 8);
  const int c = (tid * 8) & 1023;
  const float* vec = (tid < 128) ? h0v : rgm;
  const float4 x0 = *(const float4*)(vec + c);
  const float4 x1 = *(const float4*)(vec + c + 4);
  const float s = wred(dot8(v, x0, x1));
  if ((tid & 63) == 0) red[tid >> 6] = s;
  __syncthreads();
  if (tid == 0) {
    const float d = red[0] + red[1] + red[2] + red[3];
    if (id < 1024) {
      const float wg = wgv[id];
      mem_s[id] = (1.0f - wg) * mem_s[id] + wg * ftanh(b_enc[id] + Web[id] + d);
    } else {
      out_s[id - 1024] = vout[id - 1024] + d;
    }
  }
}

// ================= step-4 constants: ccat = [c_bi|c_ig|c_rg] (bf16 Wg7 weights) =========
__global__ void final_consts(const bf16* __restrict__ Wg7, const float* __restrict__ b_inp,
                             const float* __restrict__ b_rinp, const float* __restrict__ b_ig,
                             const float* __restrict__ b_mig, const float* __restrict__ b_rig,
                             const float* __restrict__ b_rg, const float* __restrict__ b_mrg,
                             const float* __restrict__ b_rrg, const float* __restrict__ out_s,
                             const float* __restrict__ mem_s, float* __restrict__ ccat) {
  __shared__ float red[5][4];
  const int id = blockIdx.x, tid = threadIdx.x, lane = tid & 63, wave = tid >> 6;
  const float4 z = make_float4(0.f, 0.f, 0.f, 0.f);
  const float4 o4 = (tid < 128) ? *(const float4*)(out_s + tid * 4) : z;
  const float4 m4 = *(const float4*)(mem_s + tid * 4);
  const bf16* rowb = Wg7 + (size_t)id * WG7_STRIDE;
  float p[5];
  p[0] = (tid < 128) ? dot4(b2f4(*(const ushort4*)(rowb + tid * 4)), o4) : 0.f;
  p[1] = dot4(b2f4(*(const ushort4*)(rowb + 512 + tid * 4)), m4);
  p[2] = (tid < 128) ? dot4(b2f4(*(const ushort4*)(rowb + 1536 + tid * 4)), o4) : 0.f;
  p[3] = dot4(b2f4(*(const ushort4*)(rowb + 2048 + tid * 4)), m4);
  p[4] = (tid < 128) ? dot4(b2f4(*(const ushort4*)(rowb + 3072 + tid * 4)), o4) : 0.f;
#pragma unroll
  for (int d = 0; d < 5; ++d) {
    float s = wred(p[d]);
    if (lane == 0) red[d][wave] = s;
  }
  __syncthreads();
  if (tid == 0) {
    float D[5];
#pragma unroll
    for (int d = 0; d < 5; ++d) D[d] = red[d][0] + red[d][1] + red[d][2] + red[d][3];
    ccat[id] = b_inp[id] + b_rinp[id] + D[0];
    ccat[1024 + id] = b_ig[id] + b_mig[id] + b_rig[id] + D[1] + D[2];
    ccat[2048 + id] = b_rg[id] + b_mrg[id] + b_rrg[id] + D[3] + D[4];
  }
}

// ================= gate GEMM: NG=3, 64x64 tile, fused sigmoid + H0 product =================
// Measured-best form: single-buffered BK=64 @4 blocks/CU (dbuf@2blk -5us R5; BK32 null R7).
// Epilogue folds mem3 into rg (rg*mem3 -> Hcat right). XCD swizzle for L2 locality.
__global__ __launch_bounds__(256, 4) void gemm_gates(const bf16* __restrict__ A,
                                                     const bf16* __restrict__ Wcat,
                                                     const float* __restrict__ ccat,
                                                     const float* __restrict__ mem_s,
                                                     bf16* __restrict__ Hcat) {
  __shared__ char smem[32768];  // A tile 8KB @0; B_g tile 8KB @ 8192+g*8192
  const int tid = threadIdx.x, wave = tid >> 6, lane = tid & 63;
  const int wm = wave >> 1, wn = wave & 1;
  const int swz = (blockIdx.x & 7) * 128 + (blockIdx.x >> 3);
  const int m0 = (swz >> 4) * 64, n0 = (swz & 15) * 64;
  f32x4 acc[3][2][2] = {};

  for (int kt = 0; kt < 512; kt += 64) {
    __syncthreads();
#pragma unroll
    for (int i = 0; i < 2; ++i) {
      const int ci = i * 256 + tid;
      const int row = ci >> 3, ck = (ci & 7) ^ (row & 7);
      const bf16* g = A + (size_t)(m0 + row) * 512 + kt + ck * 8;
      const unsigned lofs = (unsigned)__builtin_amdgcn_readfirstlane((i * 256 + wave * 64) * 16);
      __builtin_amdgcn_global_load_lds(
          (const __attribute__((address_space(1))) void*)g,
          (__attribute__((address_space(3))) void*)(smem + lofs), 16, 0, 0);
    }
#pragma unroll
    for (int gI = 0; gI < 3; ++gI) {
      const bf16* Bp = Wcat + gI * 524288;
#pragma unroll
      for (int i = 0; i < 2; ++i) {
        const int ci = i * 256 + tid;
        const int row = ci >> 3, ck = (ci & 7) ^ (row & 7);
        const bf16* g = Bp + (size_t)(n0 + row) * 512 + kt + ck * 8;
        const unsigned lofs = (unsigned)__builtin_amdgcn_readfirstlane(
            8192 + gI * 8192 + (i * 256 + wave * 64) * 16);
        __builtin_amdgcn_global_load_lds(
            (const __attribute__((address_space(1))) void*)g,
            (__attribute__((address_space(3))) void*)(smem + lofs), 16, 0, 0);
      }
    }
    __syncthreads();

#pragma unroll
    for (int ks = 0; ks < 2; ++ks) {
      const int ckk = ks * 4 + (lane >> 4);
      s16x8 af[2];
#pragma unroll
      for (int i = 0; i < 2; ++i) {
        const int R = wm * 32 + i * 16 + (lane & 15);
        af[i] = *(const s16x8*)(smem + (R * 8 + (ckk ^ (R & 7))) * 16);
      }
#pragma unroll
      for (int gI = 0; gI < 3; ++gI) {
#pragma unroll
        for (int j = 0; j < 2; ++j) {
          const int R = wn * 32 + j * 16 + (lane & 15);
          const s16x8 bfr =
              *(const s16x8*)(smem + 8192 + gI * 8192 + (R * 8 + (ckk ^ (R & 7))) * 16);
#pragma unroll
          for (int i = 0; i < 2; ++i)
            acc[gI][i][j] =
                __builtin_amdgcn_mfma_f32_16x16x32_bf16(af[i], bfr, acc[gI][i][j], 0, 0, 0);
        }
      }
    }
  }

  // epilogue: fast sigmoid (+mem3 fold on rg) -> LDS repack (stride 80) -> 16B stores
  __syncthreads();
  bf16* sm = (bf16*)smem;          // H0 tile [64][80]
  bf16* sr = (bf16*)smem + 5120;   // RG*mem3 tile [64][80]
  const int mb = (lane >> 4) * 4, nb = lane & 15;
#pragma unroll
  for (int i = 0; i < 2; ++i) {
#pragma unroll
    for (int j = 0; j < 2; ++j) {
      const int colL = wn * 32 + j * 16 + nb;
      const int jg = n0 + colL;
      const float c0 = ccat[jg], c1 = ccat[1024 + jg], c2 = ccat[2048 + jg];
      const float m3 = mem_s[jg];
#pragma unroll
      for (int r = 0; r < 4; ++r) {
        const int rowL = wm * 32 + i * 16 + mb + r;
        const float h = fsig(acc[0][i][j][r] + c0) * fsig(acc[1][i][j][r] + c1);
        const float rg = fsig(acc[2][i][j][r] + c2) * m3;
        sm[rowL * 80 + colL] = __float2bfloat16(h);
        sr[rowL * 80 + colL] = __float2bfloat16(rg);
      }
    }
  }
  __syncthreads();
#pragma unroll
  for (int pp = 0; pp < 2; ++pp) {  // 64 rows x 8 chunks = 512 chunks per tile
    const int c = pp * 256 + tid;
    const int row = c >> 3, cc = c & 7;
    const s16x8 v0 = *(const s16x8*)(sm + row * 80 + cc * 8);
    const s16x8 v1 = *(const s16x8*)(sr + row * 80 + cc * 8);
    *(s16x8*)(Hcat + (size_t)(m0 + row) * 2048 + n0 + cc * 8) = v0;
    *(s16x8*)(Hcat + (size_t)(m0 + row) * 2048 + 1024 + n0 + cc * 8) = v1;
  }
}

// ================= out GEMM: 64x64, K=2048, double-buffered, direct store + vout[col] =====
// Measured-best form (R4; R10's 32x64 @4 blocks/CU was +1.3us -> reverted).
// B = Wcat2 = [WhoB | P]; A = [H0 | rg*mem3]. XCD swizzle keeps per-XCD set in L2.
__global__ __launch_bounds__(256, 4) void gemm_out(const bf16* __restrict__ A,
                                                   const bf16* __restrict__ Bp,
                                                   const float* __restrict__ vout,
                                                   float* __restrict__ outF) {
  __shared__ char smem[32768];  // dbuf: buf0 {A@0,B@8192}, buf1 {A@16384,B@24576}
  const int tid = threadIdx.x, wave = tid >> 6, lane = tid & 63;
  const int wm = wave >> 1, wn = wave & 1;
  const int swz = (blockIdx.x & 7) * 64 + (blockIdx.x >> 3);
  const int m0 = (swz >> 3) * 64, n0 = (swz & 7) * 64;
  f32x4 acc[2][2] = {};

  auto STAGE = [&](int kt, unsigned bofs) {
#pragma unroll
    for (int i = 0; i < 2; ++i) {
      const int ci = i * 256 + tid;
      const int row = ci >> 3, ck = (ci & 7) ^ (row & 7);
      const bf16* g = A + (size_t)(m0 + row) * 2048 + kt + ck * 8;
      const unsigned lofs =
          (unsigned)__builtin_amdgcn_readfirstlane(bofs + (i * 256 + wave * 64) * 16);
      __builtin_amdgcn_global_load_lds(
          (const __attribute__((address_space(1))) void*)g,
          (__attribute__((address_space(3))) void*)(smem + lofs), 16, 0, 0);
    }
#pragma unroll
    for (int i = 0; i < 2; ++i) {
      const int ci = i * 256 + tid;
      const int row = ci >> 3, ck = (ci & 7) ^ (row & 7);
      const bf16* g = Bp + (size_t)(n0 + row) * 2048 + kt + ck * 8;
      const unsigned lofs =
          (unsigned)__builtin_amdgcn_readfirstlane(bofs + 8192 + (i * 256 + wave * 64) * 16);
      __builtin_amdgcn_global_load_lds(
          (const __attribute__((address_space(1))) void*)g,
          (__attribute__((address_space(3))) void*)(smem + lofs), 16, 0, 0);
    }
  };

  STAGE(0, 0);
  __syncthreads();
  unsigned cur = 0;
  for (int kt = 0; kt < 2048; kt += 64) {
    if (kt + 64 < 2048) STAGE(kt + 64, (cur ^ 1u) * 16384u);
#pragma unroll
    for (int ks = 0; ks < 2; ++ks) {
      const int ckk = ks * 4 + (lane >> 4);
      const unsigned cofs = cur * 16384u;
      s16x8 af[2];
#pragma unroll
      for (int i = 0; i < 2; ++i) {
        const int R = wm * 32 + i * 16 + (lane & 15);
        af[i] = *(const s16x8*)(smem + cofs + (R * 8 + (ckk ^ (R & 7))) * 16);
      }
#pragma unroll
      for (int j = 0; j < 2; ++j) {
        const int R = wn * 32 + j * 16 + (lane & 15);
        const s16x8 bfr = *(const s16x8*)(smem + cofs + 8192 + (R * 8 + (ckk ^ (R & 7))) * 16);
#pragma unroll
        for (int i = 0; i < 2; ++i)
          acc[i][j] = __builtin_amdgcn_mfma_f32_16x16x32_bf16(af[i], bfr, acc[i][j], 0, 0, 0);
      }
    }
    __syncthreads();  // drains vmcnt(0)+lgkmcnt(0): next-tile loads landed, all reads done
    cur ^= 1u;
  }

  const int mb = (lane >> 4) * 4, nb = lane & 15;
#pragma unroll
  for (int i = 0; i < 2; ++i) {
#pragma unroll
    for (int j = 0; j < 2; ++j) {
      const int col = n0 + wn * 32 + j * 16 + nb;
#pragma unroll
      for (int r = 0; r < 4; ++r) {
        const int rowg = m0 + wm * 32 + i * 16 + mb + r;
        outF[(size_t)rowg * 512 + col] = acc[i][j][r] + vout[col];
      }
    }
  }
}

extern "C" void kernel_launch(void* const* d_in, const int* in_sizes, int n_in, void* d_out,
                              int out_size, void* d_ws, size_t ws_size, hipStream_t stream) {
  const float* input  = (const float*)d_in[0];
  const float* W_ig   = (const float*)d_in[1];  const float* b_ig   = (const float*)d_in[2];
  const float* W_rig  = (const float*)d_in[3];  const float* b_rig  = (const float*)d_in[4];
  const float* W_mig  = (const float*)d_in[5];  const float* b_mig  = (const float*)d_in[6];
  const float* W_inp  = (const float*)d_in[7];  const float* b_inp  = (const float*)d_in[8];
  const float* W_rinp = (const float*)d_in[9];  const float* b_rinp = (const float*)d_in[10];
  const float* W_rg   = (const float*)d_in[11]; const float* b_rg   = (const float*)d_in[12];
  const float* W_rrg  = (const float*)d_in[13]; const float* b_rrg  = (const float*)d_in[14];
  const float* W_mrg  = (const float*)d_in[15]; const float* b_mrg  = (const float*)d_in[16];
  const float* W_dec  = (const float*)d_in[17]; const float* b_dec  = (const float*)d_in[18];
  const float* W_wg   = (const float*)d_in[19]; const float* b_wg   = (const float*)d_in[20];
  const float* W_rwg  = (const float*)d_in[21]; const float* b_rwg  = (const float*)d_in[22];
  const float* W_mwg  = (const float*)d_in[23]; const float* b_mwg  = (const float*)d_in[24];
  const float* W_enc  = (const float*)d_in[25]; const float* b_enc  = (const float*)d_in[26];
  const float* W_ho   = (const float*)d_in[27];
  (void)W_wg;  // input-side write gate weight: dead (x=0 in steps 0-3; step-4 write gate dead)

  char* ws = (char*)d_ws;
  float* out_s = (float*)(ws + 0);
  float* mem_s = (float*)(ws + 4096);
  float* rgm   = (float*)(ws + 8192);
  float* h0v   = (float*)(ws + 12288);
  float* wgv   = (float*)(ws + 16384);
  float* ccat  = (float*)(ws + 24576);   // 3072 f32
  float* vout  = (float*)(ws + 40960);   // 512 f32
  float* Web   = (float*)(ws + 45056);   // 1024 f32 (Wenc . b_dec)
  bf16* Xb     = (bf16*)(ws + 2162688);                // [4096][512] (4MB)
  bf16* Wcat   = (bf16*)(ws + 6356992);                // [3072][512] (3MB)
  bf16* Wcat2  = (bf16*)(ws + 10551296);               // [512][2048] = [Who | P] (2MB)
  bf16* Wdt    = (bf16*)(ws + 12648448);               // [1024][1024] (2MB)
  bf16* Hcat   = (bf16*)(ws + 14745600);               // [4096][2048] (16MB)
  bf16* EW2    = (bf16*)(ws + 31522816);               // [1024][2048] = [Wenc | E] (4MB)
  bf16* Wg7    = (bf16*)(ws + 37814272);               // [1024][5120] bf16 (10.5MB)

  // setup: Who/Wenc casts + Wdt transpose + merged GEMVs + step-0 update + Wg7 cast
  setup<<<9216, 256, 0, stream>>>(W_ho, W_dec, W_enc,
                                  W_rinp, W_mig, W_rig, W_mrg, W_rrg, W_mwg, W_rwg,
                                  b_inp, b_rinp, b_ig, b_mig, b_rig, b_wg, b_mwg, b_rwg,
                                  b_dec, b_enc, Wcat2, Wdt, EW2, out_s, mem_s, vout, Web, Wg7);

  // steps 1..3: gates + riders {s0: P/E GEMM, s1: Xb transpose, s2: Wcat cast}
  for (int s = 0; s < 3; ++s) {
    const int riders = (s == 0) ? 384 : (s == 1) ? 2048 : 1536;
    const int mode = s;
    gates_pe<<<1024 + riders, 256, 0, stream>>>(
        Wg7, b_inp, b_rinp, b_ig, b_mig, b_rig, b_rg, b_mrg, b_rrg, b_wg, b_mwg, b_rwg,
        out_s, mem_s, rgm, h0v, wgv, Wdt, Wcat2, EW2, input, Xb, W_inp, W_ig, W_rg, Wcat,
        riders, mode);
    step_fuse<<<1536, 256, 0, stream>>>(EW2, Wcat2, b_enc, Web, vout, rgm, h0v, wgv, mem_s,
                                        out_s);
  }

  // step-4 constants (ccat) only — M1 scaling folded into gemm_gates epilogue
  final_consts<<<1024, 256, 0, stream>>>(Wg7, b_inp, b_rinp, b_ig, b_mig, b_rig, b_rg, b_mrg,
                                         b_rrg, out_s, mem_s, ccat);

  // gates: Hcat = [sig*sig | sig*mem3] of Xb . [Wi|Wg|Wr]^T + ccat
  gemm_gates<<<1024, 256, 0, stream>>>(Xb, Wcat, ccat, mem_s, Hcat);

  // out = [H0|rg*mem3] . [Who|P]^T + vout  (direct store)
  gemm_out<<<512, 256, 0, stream>>>(Hcat, Wcat2, vout, (float*)d_out);
}